// Round 13
// baseline (138.258 us; speedup 1.0000x reference)
//
#include <hip/hip_runtime.h>
#include <hip/hip_bf16.h>

// GCN layer: out[c] = bias + dis[c]*(hs[c] + sum_{r in in(c)} hs[r]),
//            hs = (X @ W) * dis[row]  (bf16), dis = rsqrt(deg+1).
// N=50000, E=800000, D=64, fp32 in/out.
// R13: hist widened to 256 blocks (128 half-slices x {row,col}) so all CUs are
//      busy (was 128 blocks = half machine idle at the 2-blocks/CU wave limit).
//      reduce_scan merges half-slice pairs when emitting bs8, so bucket/gather
//      keep the proven 64-slice granularity. hist edge reads via int2.

constexpr int N_NODES = 50000;
constexpr int N_EDGES = 800000;
constexpr int D = 64;
constexpr int NB_SCAN = (N_NODES + 255) / 256;  // 196

constexpr int B_HIST = 128;                  // histogram half-slices
constexpr int HSLICE = N_EDGES / B_HIST;     // 6250 (exact, 8B-aligned base)
constexpr int B_SLICE = 64;                  // bucket slices (= pairs of half-slices)
constexpr int SLICE = N_EDGES / B_SLICE;     // 12500
constexpr int PACK8 = N_NODES / 4;           // 12500 u32 words (u8 x4)
constexpr int QUAR = N_NODES / 4;            // 12500 nodes per bucket quarter

static __device__ __forceinline__ unsigned short f2bf(float f) {
    unsigned u = __float_as_uint(f);
    unsigned r = (u + 0x7fffu + ((u >> 16) & 1u)) >> 16;  // RNE
    return (unsigned short)r;
}
static __device__ __forceinline__ float bf2f(unsigned short s) {
    return __uint_as_float((unsigned)s << 16);
}

// ---- 1. per-half-slice u8-packed histograms: 256 blocks, all CUs busy ----
// blocks [0,128) histogram row half-slices, [128,256) col half-slices.
// Per-half-slice-per-bin ~Poisson(0.125): u8 overflow impossible in practice.
__global__ __launch_bounds__(1024) void hist_priv_kernel(const int* __restrict__ ei,
                                                         unsigned* __restrict__ bh) {
    __shared__ unsigned loc[PACK8];  // 50 KB
    int b = blockIdx.x;
    int s = b & (B_HIST - 1);
    const int* arr = (b < B_HIST) ? ei : ei + N_EDGES;
    for (int w = threadIdx.x; w < PACK8; w += 1024) loc[w] = 0;
    __syncthreads();
    const int2* p = (const int2*)(arr + s * HSLICE);  // 6250 even, base 8B-aligned
    for (int i = threadIdx.x; i < HSLICE / 2; i += 1024) {
        int2 kk = p[i];
        atomicAdd(&loc[kk.x >> 2], 1u << (8 * (kk.x & 3)));  // LDS atomic
        atomicAdd(&loc[kk.y >> 2], 1u << (8 * (kk.y & 3)));
    }
    __syncthreads();
    unsigned* dst = bh + (size_t)b * PACK8;
    for (int w = threadIdx.x; w < PACK8; w += 1024) dst[w] = loc[w];
}

// ---- 2. reduce + dis + inline bs8 (merging half-slice pairs) + block scan ----
__global__ __launch_bounds__(256) void reduce_scan_kernel(const unsigned* __restrict__ bh,
                                                          float* __restrict__ dis,
                                                          int* __restrict__ offs_local,
                                                          int* __restrict__ partials,
                                                          unsigned char* __restrict__ bs8) {
    int t = threadIdx.x;
    int i = blockIdx.x * 256 + t;
    unsigned cl = 0;
    if (i < N_NODES) {
        const int w = i >> 2;
        const unsigned sh = 8 * (i & 3);
        const unsigned* prow = bh + w;
        unsigned dl = 0;
#pragma unroll
        for (int g = 0; g < 8; ++g) {
            unsigned vr[16];
#pragma unroll
            for (int k = 0; k < 16; ++k) vr[k] = prow[(size_t)(g * 16 + k) * PACK8];
#pragma unroll
            for (int k = 0; k < 16; ++k) dl += (vr[k] >> sh) & 0xffu;
        }
        dis[i] = rsqrtf((float)dl + 1.0f);  // +1 self loop
        const unsigned* pcol = bh + (size_t)B_HIST * PACK8 + w;
#pragma unroll
        for (int g = 0; g < 8; ++g) {
            unsigned vr[16];
#pragma unroll
            for (int k = 0; k < 16; ++k) vr[k] = pcol[(size_t)(g * 16 + k) * PACK8];
#pragma unroll
            for (int pb = 0; pb < 8; ++pb) {  // bucket slice = half-slice pair
                bs8[(size_t)(g * 8 + pb) * N_NODES + i] = (unsigned char)cl;
                cl += ((vr[2 * pb] >> sh) & 0xffu) + ((vr[2 * pb + 1] >> sh) & 0xffu);
            }
        }
    }
    __shared__ int s[256];
    s[t] = (int)cl;
    __syncthreads();
    for (int d = 1; d < 256; d <<= 1) {
        int u = (t >= d) ? s[t - d] : 0;
        __syncthreads();
        s[t] += u;
        __syncthreads();
    }
    if (i < N_NODES) offs_local[i] = s[t] - (int)cl;
    if (t == 255) partials[blockIdx.x] = s[t];
}

// ---- 3. offs: redundant partials scan + absolute offs + sentinel ----
__global__ __launch_bounds__(256) void offs_kernel(const int* __restrict__ offs_local,
                                                   const int* __restrict__ partials,
                                                   int* __restrict__ offs) {
    __shared__ int pref[256];
    int t = threadIdx.x;
    int v = (t < NB_SCAN) ? partials[t] : 0;
    pref[t] = v;
    __syncthreads();
    for (int d = 1; d < 256; d <<= 1) {
        int u = (t >= d) ? pref[t - d] : 0;
        __syncthreads();
        pref[t] += u;
        __syncthreads();
    }
    int ex = pref[t] - v;
    __syncthreads();
    pref[t] = ex;
    __syncthreads();
    int i = blockIdx.x * 256 + t;
    if (i < N_NODES) offs[i] = pref[blockIdx.x] + offs_local[i];
    if (i == 0) offs[N_NODES] = N_EDGES;  // sentinel
}

// ---- 4. gemm: 64x64 tile, 4x4 reg tile, hs = bf16(h*dis[row]) (R12 proven) ----
__global__ __launch_bounds__(256, 4) void gemm_kernel(const float* __restrict__ x,
                                                      const float* __restrict__ W,
                                                      const float* __restrict__ dis,
                                                      unsigned short* __restrict__ hs) {
    __shared__ float Xs[64][68];  // pad: 2-way max bank alias = free
    __shared__ float Ws[64][64];
    int t = threadIdx.x;
    int n0 = blockIdx.x * 64;

    const float4* W4 = (const float4*)W;
    float4* Ws4 = (float4*)Ws;
#pragma unroll
    for (int i = 0; i < 4; ++i) Ws4[t + i * 256] = W4[t + i * 256];

    const float4* x4 = (const float4*)(x + (size_t)n0 * D);
#pragma unroll
    for (int i = 0; i < 4; ++i) {
        int f = t + i * 256;
        int r = f >> 4, c = (f & 15) << 2;
        float4 v = make_float4(0.f, 0.f, 0.f, 0.f);
        if (n0 + r < N_NODES) v = x4[f];
        Xs[r][c] = v.x; Xs[r][c + 1] = v.y; Xs[r][c + 2] = v.z; Xs[r][c + 3] = v.w;
    }
    __syncthreads();

    int tx = t & 15, ty = t >> 4;
    float acc[4][4] = {};
#pragma unroll 8
    for (int k = 0; k < D; ++k) {
        float a[4], bb[4];
#pragma unroll
        for (int i = 0; i < 4; ++i) a[i] = Xs[ty * 4 + i][k];
#pragma unroll
        for (int jj = 0; jj < 4; ++jj) bb[jj] = Ws[k][tx * 4 + jj];
#pragma unroll
        for (int i = 0; i < 4; ++i)
#pragma unroll
            for (int jj = 0; jj < 4; ++jj)
                acc[i][jj] = fmaf(a[i], bb[jj], acc[i][jj]);
    }

#pragma unroll
    for (int i = 0; i < 4; ++i) {
        int r = ty * 4 + i;
        if (n0 + r < N_NODES) {
            float dr = dis[n0 + r];
            ushort4 v;
            v.x = f2bf(acc[i][0] * dr); v.y = f2bf(acc[i][1] * dr);
            v.z = f2bf(acc[i][2] * dr); v.w = f2bf(acc[i][3] * dr);
            *(ushort4*)(hs + (size_t)(n0 + r) * D + tx * 4) = v;
        }
    }
}

// ---- 5. deterministic bucket: 64 slices x 4 quarters, pos = offs + u8 rel ----
__global__ __launch_bounds__(1024) void bucket_det_kernel(const int* __restrict__ ei,
                                                          const int* __restrict__ offs,
                                                          const unsigned char* __restrict__ bs8,
                                                          int* __restrict__ csr) {
    __shared__ unsigned pos[QUAR];  // 50 KB
    const int s = blockIdx.x >> 2;
    const int q = blockIdx.x & 3;
    const int c0 = q * QUAR;
    const int* offq = offs + c0;
    const unsigned char* relq = bs8 + (size_t)s * N_NODES + c0;
    for (int w = threadIdx.x; w < QUAR; w += 1024)
        pos[w] = (unsigned)offq[w] + relq[w];
    __syncthreads();
    const int* rowp = ei + s * SLICE;
    const int* colp = ei + N_EDGES + s * SLICE;
    for (int i = threadIdx.x; i < SLICE; i += 1024) {
        int c = colp[i];
        if (c >= c0 && c < c0 + QUAR) {
            unsigned p = atomicAdd(&pos[c - c0], 1u);  // LDS atomic
            csr[p] = rowp[i];
        }
    }
}

// ---- 6. gather: wave per node, scalar csr loads, MLP 16 (R8/R12 proven) ----
__global__ __launch_bounds__(256) void gather_kernel(const int* __restrict__ offs,
                                                     const int* __restrict__ csr,
                                                     const unsigned short* __restrict__ hs,
                                                     const float* __restrict__ dis,
                                                     const float* __restrict__ bias,
                                                     float* __restrict__ out) {
    int wave = threadIdx.x >> 6;
    int j = threadIdx.x & 63;
    int n = blockIdx.x * 4 + wave;
    if (n >= N_NODES) return;

    float a[8];
    a[0] = bf2f(hs[(size_t)n * D + j]);  // self loop (dis[n]*h[n])
#pragma unroll
    for (int k = 1; k < 8; ++k) a[k] = 0.f;

    // wave-uniform (SGPR) csr addressing -> scalar loads, free broadcast
    int beg = __builtin_amdgcn_readfirstlane(offs[n]);
    int m   = __builtin_amdgcn_readfirstlane(offs[n + 1]) - beg;
    const int* p = csr + beg;

    int i = 0;
    for (; i + 16 <= m; i += 16) {
        int r[16];
        float v[16];
#pragma unroll
        for (int k = 0; k < 16; ++k) r[k] = p[i + k];
#pragma unroll
        for (int k = 0; k < 16; ++k) v[k] = bf2f(hs[(size_t)r[k] * D + j]);  // 16 in flight
#pragma unroll
        for (int k = 0; k < 16; ++k) a[k & 7] += v[k];
    }
    for (; i + 4 <= m; i += 4) {
        int r0 = p[i], r1 = p[i + 1], r2 = p[i + 2], r3 = p[i + 3];
        a[0] += bf2f(hs[(size_t)r0 * D + j]);
        a[1] += bf2f(hs[(size_t)r1 * D + j]);
        a[2] += bf2f(hs[(size_t)r2 * D + j]);
        a[3] += bf2f(hs[(size_t)r3 * D + j]);
    }
    for (; i < m; ++i) a[1] += bf2f(hs[(size_t)p[i] * D + j]);
    float tot = ((a[0] + a[1]) + (a[2] + a[3])) + ((a[4] + a[5]) + (a[6] + a[7]));
    out[(size_t)n * D + j] = fmaf(dis[n], tot, bias[j]);
}

// ======================= fallback (atomic) build path =======================

__global__ void histf_kernel(const int* __restrict__ row, const int* __restrict__ col,
                             int* __restrict__ degi, int* __restrict__ cnt) {
    int e = blockIdx.x * blockDim.x + threadIdx.x;
    if (e < N_EDGES) {
        atomicAdd(&degi[row[e]], 1);
        atomicAdd(&cnt[col[e]], 1);
    }
}

__global__ void disf_kernel(int* __restrict__ degi) {
    int i = blockIdx.x * blockDim.x + threadIdx.x;
    if (i < N_NODES) {
        float d = (float)degi[i] + 1.0f;
        ((float*)degi)[i] = rsqrtf(d);
    }
}

__global__ void block_scan_kernel(const int* __restrict__ cnt, int* __restrict__ offs,
                                  int* __restrict__ partials) {
    __shared__ int s[256];
    int t = threadIdx.x;
    int i = blockIdx.x * 256 + t;
    int v = (i < N_NODES) ? cnt[i] : 0;
    s[t] = v;
    __syncthreads();
    for (int d = 1; d < 256; d <<= 1) {
        int u = (t >= d) ? s[t - d] : 0;
        __syncthreads();
        s[t] += u;
        __syncthreads();
    }
    if (i < N_NODES) offs[i] = s[t] - v;
    if (t == 255) partials[blockIdx.x] = s[t];
}

__global__ void scan_partials_kernel(int* __restrict__ partials) {
    __shared__ int s[256];
    int t = threadIdx.x;
    int v = (t < NB_SCAN) ? partials[t] : 0;
    s[t] = v;
    __syncthreads();
    for (int d = 1; d < 256; d <<= 1) {
        int u = (t >= d) ? s[t - d] : 0;
        __syncthreads();
        s[t] += u;
        __syncthreads();
    }
    if (t < NB_SCAN) partials[t] = s[t] - v;
}

__global__ void add_off_kernel(int* __restrict__ offs, const int* __restrict__ partials) {
    int i = blockIdx.x * 256 + threadIdx.x;
    if (i < N_NODES) offs[i] += partials[blockIdx.x];
    if (i == 0) offs[N_NODES] = N_EDGES;
}

__global__ void bucket_fb_kernel(const int* __restrict__ row, const int* __restrict__ col,
                                 const int* __restrict__ offs, int* __restrict__ cur,
                                 int* __restrict__ csr) {
    int e = blockIdx.x * blockDim.x + threadIdx.x;
    if (e < N_EDGES) {
        int c = col[e];
        int pos = offs[c] + atomicAdd(&cur[c], 1);
        csr[pos] = row[e];
    }
}

// ======================= launch =======================

extern "C" void kernel_launch(void* const* d_in, const int* in_sizes, int n_in,
                              void* d_out, int out_size, void* d_ws, size_t ws_size,
                              hipStream_t stream) {
    const float* x    = (const float*)d_in[0];
    const int*   ei   = (const int*)d_in[1];
    const float* W    = (const float*)d_in[2];
    const float* bias = (const float*)d_in[3];
    float* out = (float*)d_out;

    // workspace layout (bytes):
    //   [0        ..   200000)  dis / degi (fallback)
    //   [200000   ..   400064)  offs (N+1 ints)
    //   [400064   ..   600064)  offs_local / cnt (fallback)
    //   [600064   ..   800064)  cur (fallback only)
    //   [800064   ..   801088)  partials
    //   [801088   ..  4001088)  csr (800000 x int)
    //   [4001088  .. 10401088)  hs (50000 x 64 bf16)
    //   [10401088 .. 23201088)  bh (256 x 12500 u32, u8-packed)
    //   [23201088 .. 26401088)  bs8 (64 x 50000 u8, relative)
    char* ws = (char*)d_ws;
    float*          dis      = (float*)(ws + 0);
    int*            offs     = (int*)(ws + 200000);
    int*            offs_loc = (int*)(ws + 400064);
    int*            cur      = (int*)(ws + 600064);
    int*            partials = (int*)(ws + 800064);
    int*            csr      = (int*)(ws + 801088);
    unsigned short* hs       = (unsigned short*)(ws + 4001088);
    unsigned*       bh       = (unsigned*)(ws + 10401088);
    unsigned char*  bs8      = (unsigned char*)(ws + 23201088);

    const size_t WS_NEEDED = 26401088;

    if (ws_size >= WS_NEEDED) {
        hist_priv_kernel<<<2 * B_HIST, 1024, 0, stream>>>(ei, bh);
        reduce_scan_kernel<<<NB_SCAN, 256, 0, stream>>>(bh, dis, offs_loc, partials, bs8);
        offs_kernel<<<NB_SCAN, 256, 0, stream>>>(offs_loc, partials, offs);
        gemm_kernel<<<(N_NODES + 63) / 64, 256, 0, stream>>>(x, W, dis, hs);
        bucket_det_kernel<<<4 * B_SLICE, 1024, 0, stream>>>(ei, offs, bs8, csr);
        gather_kernel<<<(N_NODES + 3) / 4, 256, 0, stream>>>(offs, csr, hs, dis, bias, out);
    } else {
        const int* row = ei;
        const int* col = ei + N_EDGES;
        int* degi = (int*)dis;
        int* cntf = offs_loc;
        hipMemsetAsync(ws, 0, 800064, stream);
        histf_kernel<<<(N_EDGES + 255) / 256, 256, 0, stream>>>(row, col, degi, cntf);
        disf_kernel<<<(N_NODES + 255) / 256, 256, 0, stream>>>(degi);
        block_scan_kernel<<<NB_SCAN, 256, 0, stream>>>(cntf, offs, partials);
        scan_partials_kernel<<<1, 256, 0, stream>>>(partials);
        add_off_kernel<<<NB_SCAN, 256, 0, stream>>>(offs, partials);
        gemm_kernel<<<(N_NODES + 63) / 64, 256, 0, stream>>>(x, W, dis, hs);
        bucket_fb_kernel<<<(N_EDGES + 255) / 256, 256, 0, stream>>>(row, col, offs, cur, csr);
        gather_kernel<<<(N_NODES + 3) / 4, 256, 0, stream>>>(offs, csr, hs, dis, bias, out);
    }
}

// Round 14
// 133.299 us; speedup vs baseline: 1.0372x; 1.0372x over previous
//
#include <hip/hip_runtime.h>
#include <hip/hip_bf16.h>

// GCN layer: out[c] = bias + dis[c]*(hs[c] + sum_{r in in(c)} hs[r]),
//            hs = (X @ W) * dis[row]  (bf16), dis = rsqrt(deg+1).
// N=50000, E=800000, D=64, fp32 in/out.
// R14: R12 config (best: 133.7us; R13's wider hist regressed -- more bh bytes
//      beat the occupancy gain) minus the offs dispatch: bucket_det scans the
//      196 partials in LDS per block, computes absolute offsets inline, and
//      its s==0 blocks write offs (+sentinel) for gather. 5 dispatches.

constexpr int N_NODES = 50000;
constexpr int N_EDGES = 800000;
constexpr int D = 64;
constexpr int NB_SCAN = (N_NODES + 255) / 256;  // 196

constexpr int B_SLICE = 64;                  // edge slices
constexpr int SLICE = N_EDGES / B_SLICE;     // 12500 (exact)
constexpr int PACK8 = N_NODES / 4;           // 12500 u32 words (u8 x4)
constexpr int QUAR = N_NODES / 4;            // 12500 nodes per bucket quarter

static __device__ __forceinline__ unsigned short f2bf(float f) {
    unsigned u = __float_as_uint(f);
    unsigned r = (u + 0x7fffu + ((u >> 16) & 1u)) >> 16;  // RNE
    return (unsigned short)r;
}
static __device__ __forceinline__ float bf2f(unsigned short s) {
    return __uint_as_float((unsigned)s << 16);
}

// ---- 1. per-slice u8-packed histograms (R12 proven) ----
__global__ __launch_bounds__(1024) void hist_priv_kernel(const int* __restrict__ ei,
                                                         unsigned* __restrict__ bh) {
    __shared__ unsigned loc[PACK8];  // 50 KB
    int b = blockIdx.x;
    int s = b & (B_SLICE - 1);
    const int* arr = (b < B_SLICE) ? ei : ei + N_EDGES;
    for (int w = threadIdx.x; w < PACK8; w += 1024) loc[w] = 0;
    __syncthreads();
    const int* p = arr + s * SLICE;
    for (int i = threadIdx.x; i < SLICE; i += 1024) {
        int k = p[i];
        atomicAdd(&loc[k >> 2], 1u << (8 * (k & 3)));  // LDS atomic, ~Poisson(.25)/bin
    }
    __syncthreads();
    unsigned* dst = bh + (size_t)b * PACK8;
    for (int w = threadIdx.x; w < PACK8; w += 1024) dst[w] = loc[w];
}

// ---- 2. reduce + dis + inline bs8 + block-local scan (R12 proven) ----
__global__ __launch_bounds__(256) void reduce_scan_kernel(const unsigned* __restrict__ bh,
                                                          float* __restrict__ dis,
                                                          int* __restrict__ offs_local,
                                                          int* __restrict__ partials,
                                                          unsigned char* __restrict__ bs8) {
    int t = threadIdx.x;
    int i = blockIdx.x * 256 + t;
    unsigned cl = 0;
    if (i < N_NODES) {
        const int w = i >> 2;
        const unsigned sh = 8 * (i & 3);
        const unsigned* prow = bh + w;
        unsigned dl = 0;
#pragma unroll
        for (int g = 0; g < 4; ++g) {
            unsigned vr[16];
#pragma unroll
            for (int k = 0; k < 16; ++k) vr[k] = prow[(size_t)(g * 16 + k) * PACK8];
#pragma unroll
            for (int k = 0; k < 16; ++k) dl += (vr[k] >> sh) & 0xffu;
        }
        dis[i] = rsqrtf((float)dl + 1.0f);  // +1 self loop
        const unsigned* pcol = bh + (size_t)B_SLICE * PACK8 + w;
#pragma unroll
        for (int g = 0; g < 4; ++g) {
            unsigned vr[16];
#pragma unroll
            for (int k = 0; k < 16; ++k) vr[k] = pcol[(size_t)(g * 16 + k) * PACK8];
#pragma unroll
            for (int k = 0; k < 16; ++k) {
                bs8[(size_t)(g * 16 + k) * N_NODES + i] = (unsigned char)cl;  // rel start
                cl += (vr[k] >> sh) & 0xffu;
            }
        }
    }
    __shared__ int s[256];
    s[t] = (int)cl;
    __syncthreads();
    for (int d = 1; d < 256; d <<= 1) {
        int u = (t >= d) ? s[t - d] : 0;
        __syncthreads();
        s[t] += u;
        __syncthreads();
    }
    if (i < N_NODES) offs_local[i] = s[t] - (int)cl;
    if (t == 255) partials[blockIdx.x] = s[t];
}

// ---- 3. gemm: 64x64 tile, 4x4 reg tile, hs = bf16(h*dis[row]) (R12 proven) ----
__global__ __launch_bounds__(256, 4) void gemm_kernel(const float* __restrict__ x,
                                                      const float* __restrict__ W,
                                                      const float* __restrict__ dis,
                                                      unsigned short* __restrict__ hs) {
    __shared__ float Xs[64][68];  // pad: 2-way max bank alias = free
    __shared__ float Ws[64][64];
    int t = threadIdx.x;
    int n0 = blockIdx.x * 64;

    const float4* W4 = (const float4*)W;
    float4* Ws4 = (float4*)Ws;
#pragma unroll
    for (int i = 0; i < 4; ++i) Ws4[t + i * 256] = W4[t + i * 256];

    const float4* x4 = (const float4*)(x + (size_t)n0 * D);
#pragma unroll
    for (int i = 0; i < 4; ++i) {
        int f = t + i * 256;
        int r = f >> 4, c = (f & 15) << 2;
        float4 v = make_float4(0.f, 0.f, 0.f, 0.f);
        if (n0 + r < N_NODES) v = x4[f];
        Xs[r][c] = v.x; Xs[r][c + 1] = v.y; Xs[r][c + 2] = v.z; Xs[r][c + 3] = v.w;
    }
    __syncthreads();

    int tx = t & 15, ty = t >> 4;
    float acc[4][4] = {};
#pragma unroll 8
    for (int k = 0; k < D; ++k) {
        float a[4], bb[4];
#pragma unroll
        for (int i = 0; i < 4; ++i) a[i] = Xs[ty * 4 + i][k];
#pragma unroll
        for (int jj = 0; jj < 4; ++jj) bb[jj] = Ws[k][tx * 4 + jj];
#pragma unroll
        for (int i = 0; i < 4; ++i)
#pragma unroll
            for (int jj = 0; jj < 4; ++jj)
                acc[i][jj] = fmaf(a[i], bb[jj], acc[i][jj]);
    }

#pragma unroll
    for (int i = 0; i < 4; ++i) {
        int r = ty * 4 + i;
        if (n0 + r < N_NODES) {
            float dr = dis[n0 + r];
            ushort4 v;
            v.x = f2bf(acc[i][0] * dr); v.y = f2bf(acc[i][1] * dr);
            v.z = f2bf(acc[i][2] * dr); v.w = f2bf(acc[i][3] * dr);
            *(ushort4*)(hs + (size_t)(n0 + r) * D + tx * 4) = v;
        }
    }
}

// ---- 4. bucket + offs: per-block partials scan (196 ints, LDS), absolute
//         pos = pref + offs_local + u8 rel; s==0 blocks also write offs ----
__global__ __launch_bounds__(1024) void bucket_det_kernel(const int* __restrict__ ei,
                                                          const int* __restrict__ offs_local,
                                                          const int* __restrict__ partials,
                                                          const unsigned char* __restrict__ bs8,
                                                          int* __restrict__ csr,
                                                          int* __restrict__ offs) {
    __shared__ unsigned pos[QUAR];  // 50 KB
    __shared__ int pref[256];       // exclusive-scanned partials
    const int t = threadIdx.x;

    if (t < 256) pref[t] = (t < NB_SCAN) ? partials[t] : 0;
    __syncthreads();
    for (int d = 1; d < 256; d <<= 1) {
        int u = 0;
        if (t < 256 && t >= d) u = pref[t - d];
        __syncthreads();
        if (t < 256) pref[t] += u;
        __syncthreads();
    }
    if (t < 256) {
        int inc = pref[t];
        int own = (t < NB_SCAN) ? partials[t] : 0;
        pref[t] = inc - own;  // exclusive
    }
    __syncthreads();

    const int s = blockIdx.x >> 2;
    const int q = blockIdx.x & 3;
    const int c0 = q * QUAR;
    const int* olq = offs_local + c0;
    const unsigned char* relq = bs8 + (size_t)s * N_NODES + c0;
    const bool write_offs = (s == 0);
    for (int w = t; w < QUAR; w += 1024) {
        int node = c0 + w;
        int off = pref[node >> 8] + olq[w];
        pos[w] = (unsigned)off + relq[w];
        if (write_offs) offs[node] = off;
    }
    if (write_offs && q == 3 && t == 0) offs[N_NODES] = N_EDGES;  // sentinel
    __syncthreads();

    const int* rowp = ei + s * SLICE;
    const int* colp = ei + N_EDGES + s * SLICE;
    for (int i = t; i < SLICE; i += 1024) {
        int c = colp[i];
        if (c >= c0 && c < c0 + QUAR) {
            unsigned p = atomicAdd(&pos[c - c0], 1u);  // LDS atomic
            csr[p] = rowp[i];
        }
    }
}

// ---- 5. gather: wave per node, scalar csr loads, MLP 16 (R12 proven) ----
__global__ __launch_bounds__(256) void gather_kernel(const int* __restrict__ offs,
                                                     const int* __restrict__ csr,
                                                     const unsigned short* __restrict__ hs,
                                                     const float* __restrict__ dis,
                                                     const float* __restrict__ bias,
                                                     float* __restrict__ out) {
    int wave = threadIdx.x >> 6;
    int j = threadIdx.x & 63;
    int n = blockIdx.x * 4 + wave;
    if (n >= N_NODES) return;

    float a[8];
    a[0] = bf2f(hs[(size_t)n * D + j]);  // self loop (dis[n]*h[n])
#pragma unroll
    for (int k = 1; k < 8; ++k) a[k] = 0.f;

    // wave-uniform (SGPR) csr addressing -> scalar loads, free broadcast
    int beg = __builtin_amdgcn_readfirstlane(offs[n]);
    int m   = __builtin_amdgcn_readfirstlane(offs[n + 1]) - beg;
    const int* p = csr + beg;

    int i = 0;
    for (; i + 16 <= m; i += 16) {
        int r[16];
        float v[16];
#pragma unroll
        for (int k = 0; k < 16; ++k) r[k] = p[i + k];
#pragma unroll
        for (int k = 0; k < 16; ++k) v[k] = bf2f(hs[(size_t)r[k] * D + j]);  // 16 in flight
#pragma unroll
        for (int k = 0; k < 16; ++k) a[k & 7] += v[k];
    }
    for (; i + 4 <= m; i += 4) {
        int r0 = p[i], r1 = p[i + 1], r2 = p[i + 2], r3 = p[i + 3];
        a[0] += bf2f(hs[(size_t)r0 * D + j]);
        a[1] += bf2f(hs[(size_t)r1 * D + j]);
        a[2] += bf2f(hs[(size_t)r2 * D + j]);
        a[3] += bf2f(hs[(size_t)r3 * D + j]);
    }
    for (; i < m; ++i) a[1] += bf2f(hs[(size_t)p[i] * D + j]);
    float tot = ((a[0] + a[1]) + (a[2] + a[3])) + ((a[4] + a[5]) + (a[6] + a[7]));
    out[(size_t)n * D + j] = fmaf(dis[n], tot, bias[j]);
}

// ======================= fallback (atomic) build path =======================

__global__ void histf_kernel(const int* __restrict__ row, const int* __restrict__ col,
                             int* __restrict__ degi, int* __restrict__ cnt) {
    int e = blockIdx.x * blockDim.x + threadIdx.x;
    if (e < N_EDGES) {
        atomicAdd(&degi[row[e]], 1);
        atomicAdd(&cnt[col[e]], 1);
    }
}

__global__ void disf_kernel(int* __restrict__ degi) {
    int i = blockIdx.x * blockDim.x + threadIdx.x;
    if (i < N_NODES) {
        float d = (float)degi[i] + 1.0f;
        ((float*)degi)[i] = rsqrtf(d);
    }
}

__global__ void block_scan_kernel(const int* __restrict__ cnt, int* __restrict__ offs,
                                  int* __restrict__ partials) {
    __shared__ int s[256];
    int t = threadIdx.x;
    int i = blockIdx.x * 256 + t;
    int v = (i < N_NODES) ? cnt[i] : 0;
    s[t] = v;
    __syncthreads();
    for (int d = 1; d < 256; d <<= 1) {
        int u = (t >= d) ? s[t - d] : 0;
        __syncthreads();
        s[t] += u;
        __syncthreads();
    }
    if (i < N_NODES) offs[i] = s[t] - v;
    if (t == 255) partials[blockIdx.x] = s[t];
}

__global__ void scan_partials_kernel(int* __restrict__ partials) {
    __shared__ int s[256];
    int t = threadIdx.x;
    int v = (t < NB_SCAN) ? partials[t] : 0;
    s[t] = v;
    __syncthreads();
    for (int d = 1; d < 256; d <<= 1) {
        int u = (t >= d) ? s[t - d] : 0;
        __syncthreads();
        s[t] += u;
        __syncthreads();
    }
    if (t < NB_SCAN) partials[t] = s[t] - v;
}

__global__ void add_off_kernel(int* __restrict__ offs, const int* __restrict__ partials) {
    int i = blockIdx.x * 256 + threadIdx.x;
    if (i < N_NODES) offs[i] += partials[blockIdx.x];
    if (i == 0) offs[N_NODES] = N_EDGES;
}

__global__ void bucket_fb_kernel(const int* __restrict__ row, const int* __restrict__ col,
                                 const int* __restrict__ offs, int* __restrict__ cur,
                                 int* __restrict__ csr) {
    int e = blockIdx.x * blockDim.x + threadIdx.x;
    if (e < N_EDGES) {
        int c = col[e];
        int pos = offs[c] + atomicAdd(&cur[c], 1);
        csr[pos] = row[e];
    }
}

// ======================= launch =======================

extern "C" void kernel_launch(void* const* d_in, const int* in_sizes, int n_in,
                              void* d_out, int out_size, void* d_ws, size_t ws_size,
                              hipStream_t stream) {
    const float* x    = (const float*)d_in[0];
    const int*   ei   = (const int*)d_in[1];
    const float* W    = (const float*)d_in[2];
    const float* bias = (const float*)d_in[3];
    float* out = (float*)d_out;

    // workspace layout (bytes):
    //   [0        ..   200000)  dis / degi (fallback)
    //   [200000   ..   400064)  offs (N+1 ints)
    //   [400064   ..   600064)  offs_local / cnt (fallback)
    //   [600064   ..   800064)  cur (fallback only)
    //   [800064   ..   801088)  partials
    //   [801088   ..  4001088)  csr (800000 x int)
    //   [4001088  .. 10401088)  hs (50000 x 64 bf16)
    //   [10401088 .. 16801088)  bh (128 x 12500 u32, u8-packed)
    //   [16801088 .. 20001088)  bs8 (64 x 50000 u8, relative)
    char* ws = (char*)d_ws;
    float*          dis      = (float*)(ws + 0);
    int*            offs     = (int*)(ws + 200000);
    int*            offs_loc = (int*)(ws + 400064);
    int*            cur      = (int*)(ws + 600064);
    int*            partials = (int*)(ws + 800064);
    int*            csr      = (int*)(ws + 801088);
    unsigned short* hs       = (unsigned short*)(ws + 4001088);
    unsigned*       bh       = (unsigned*)(ws + 10401088);
    unsigned char*  bs8      = (unsigned char*)(ws + 16801088);

    const size_t WS_NEEDED = 20001088;

    if (ws_size >= WS_NEEDED) {
        hist_priv_kernel<<<2 * B_SLICE, 1024, 0, stream>>>(ei, bh);
        reduce_scan_kernel<<<NB_SCAN, 256, 0, stream>>>(bh, dis, offs_loc, partials, bs8);
        gemm_kernel<<<(N_NODES + 63) / 64, 256, 0, stream>>>(x, W, dis, hs);
        bucket_det_kernel<<<4 * B_SLICE, 1024, 0, stream>>>(ei, offs_loc, partials, bs8,
                                                            csr, offs);
        gather_kernel<<<(N_NODES + 3) / 4, 256, 0, stream>>>(offs, csr, hs, dis, bias, out);
    } else {
        const int* row = ei;
        const int* col = ei + N_EDGES;
        int* degi = (int*)dis;
        int* cntf = offs_loc;
        hipMemsetAsync(ws, 0, 800064, stream);
        histf_kernel<<<(N_EDGES + 255) / 256, 256, 0, stream>>>(row, col, degi, cntf);
        disf_kernel<<<(N_NODES + 255) / 256, 256, 0, stream>>>(degi);
        block_scan_kernel<<<NB_SCAN, 256, 0, stream>>>(cntf, offs, partials);
        scan_partials_kernel<<<1, 256, 0, stream>>>(partials);
        add_off_kernel<<<NB_SCAN, 256, 0, stream>>>(offs, partials);
        gemm_kernel<<<(N_NODES + 63) / 64, 256, 0, stream>>>(x, W, dis, hs);
        bucket_fb_kernel<<<(N_EDGES + 255) / 256, 256, 0, stream>>>(row, col, offs, cur, csr);
        gather_kernel<<<(N_NODES + 3) / 4, 256, 0, stream>>>(offs, csr, hs, dis, bias, out);
    }
}